// Round 2
// baseline (7437.051 us; speedup 1.0000x reference)
//
#include <hip/hip_runtime.h>

// DistributionTracker: per-label scatter-add of [count | sum(X) | sum(X^2)]
// X: (N, 128) fp32, labels: (N,) int32, out: (classes, 257) fp32 row-major.
//
// Fast path (needs ws >= 1024 + 4*N bytes):
//   k1 histogram labels into 16 class-groups
//   k2 exclusive prefix -> bucket offsets + cursors
//   k3 scatter packed (row<<6 | local_class) into group buckets
//   k4 dense gather: 8 rows/step/wave (8 lanes x float4 per row), LDS
//      privatized 63-class partials, atomic flush to global
// Fallback path: round-1 ballot-scan kernel (correct, slow).

constexpr int DIM    = 128;
constexpr int ROWLEN = 2 * DIM + 1;    // 257: [num | miu(128) | sqr(128)]
constexpr int CG     = 63;             // classes per group (63*257*4 = 64764 B LDS)

// ---------------------------------------------------------------- binning --
__global__ void hist_kernel(const int* __restrict__ labels, int N, int classes,
                            unsigned* __restrict__ hist)
{
    __shared__ unsigned lh[64];
    if (threadIdx.x < 64) lh[threadIdx.x] = 0;
    __syncthreads();
    for (int i = blockIdx.x * blockDim.x + threadIdx.x; i < N;
         i += gridDim.x * blockDim.x) {
        const unsigned lab = (unsigned)labels[i];
        if (lab < (unsigned)classes) atomicAdd(&lh[lab / CG], 1u);
    }
    __syncthreads();
    if (threadIdx.x < 64 && lh[threadIdx.x])
        atomicAdd(&hist[threadIdx.x], lh[threadIdx.x]);
}

__global__ void prefix_kernel(const unsigned* __restrict__ hist,
                              unsigned* __restrict__ off,
                              unsigned* __restrict__ cursor, int groups)
{
    if (threadIdx.x == 0 && blockIdx.x == 0) {
        unsigned s = 0;
        for (int g = 0; g < groups; ++g) {
            off[g] = s; cursor[g] = s; s += hist[g];
        }
        off[groups] = s;
    }
}

constexpr int SCAT_T  = 256;
constexpr int SCAT_IT = 16;            // 4096 rows per block

__global__ void scatter_kernel(const int* __restrict__ labels, int N, int classes,
                               unsigned* __restrict__ cursor,
                               unsigned* __restrict__ idx)
{
    __shared__ unsigned lh[64], lbase[64];
    const int tid  = threadIdx.x;
    const int tile = blockIdx.x * (SCAT_T * SCAT_IT);
    if (tid < 64) lh[tid] = 0;
    __syncthreads();

    int lab[SCAT_IT];
    for (int k = 0; k < SCAT_IT; ++k) {
        const int row = tile + k * SCAT_T + tid;
        lab[k] = -1;
        if (row < N) {
            const unsigned l = (unsigned)labels[row];
            if (l < (unsigned)classes) { lab[k] = (int)l; atomicAdd(&lh[l / CG], 1u); }
        }
    }
    __syncthreads();
    if (tid < 64) {
        if (lh[tid]) lbase[tid] = atomicAdd(&cursor[tid], lh[tid]);
        lh[tid] = 0;
    }
    __syncthreads();
    for (int k = 0; k < SCAT_IT; ++k) {
        if (lab[k] >= 0) {
            const unsigned l  = (unsigned)lab[k];
            const unsigned g  = l / CG;
            const unsigned lc = l - g * CG;
            const unsigned row = (unsigned)(tile + k * SCAT_T + tid);
            const unsigned pos = lbase[g] + atomicAdd(&lh[g], 1u);
            idx[pos] = (row << 6) | lc;
        }
    }
}

// ------------------------------------------------------------- accumulate --
constexpr int T2    = 512;             // 8 waves
constexpr int W2    = T2 / 64;
constexpr int SLICE = 8192;            // rows per block

__global__ __launch_bounds__(T2, 2)
void accum_kernel(const float* __restrict__ X,
                  const unsigned* __restrict__ gidx,
                  const unsigned* __restrict__ off,
                  float* __restrict__ out, int classes)
{
    const int g = blockIdx.y;
    const unsigned start = off[g];
    const unsigned cnt   = off[g + 1] - start;
    if ((unsigned)blockIdx.x * SLICE >= cnt) return;   // before LDS touch

    __shared__ float part[CG * ROWLEN];
    const int tid  = threadIdx.x;
    const int lane = tid & 63;
    const int wid  = tid >> 6;
    const int sub  = lane >> 3;        // row-slot 0..7 within a step
    const int l8   = lane & 7;         // lane within row

    for (int i = tid; i < CG * ROWLEN; i += T2) part[i] = 0.0f;
    __syncthreads();

    const unsigned s0 = (unsigned)blockIdx.x * SLICE;
    const unsigned e  = min(s0 + (unsigned)SLICE, cnt);

    for (unsigned p = s0 + (unsigned)wid * 64u; p < e; p += (unsigned)W2 * 64u) {
        const unsigned nb = min(64u, e - p);
#pragma unroll 2
        for (int s = 0; s < 8; ++s) {
            const unsigned slot = (unsigned)(s * 8 + sub);
            const bool v = slot < nb;
            unsigned en = 0;
            if (v) en = gidx[start + p + slot];        // 8-way broadcast, L1-hit
            const unsigned ridx = en >> 6;
            const int      lc   = (int)(en & 63u);
            const float4*  Xr   = (const float4*)(X + (size_t)ridx * DIM);
            float4 a0, a1, a2, a3;
            if (v) { a0 = Xr[l8]; a1 = Xr[l8 + 8]; a2 = Xr[l8 + 16]; a3 = Xr[l8 + 24]; }
            if (v) {
                float* pc = &part[lc * ROWLEN];
                float* pm = pc + 1   + 4 * l8;         // miu base for this lane
                float* ps = pc + 129 + 4 * l8;         // sqr base for this lane
                unsafeAtomicAdd(pm +  0, a0.x); unsafeAtomicAdd(pm +  1, a0.y);
                unsafeAtomicAdd(pm +  2, a0.z); unsafeAtomicAdd(pm +  3, a0.w);
                unsafeAtomicAdd(pm + 32, a1.x); unsafeAtomicAdd(pm + 33, a1.y);
                unsafeAtomicAdd(pm + 34, a1.z); unsafeAtomicAdd(pm + 35, a1.w);
                unsafeAtomicAdd(pm + 64, a2.x); unsafeAtomicAdd(pm + 65, a2.y);
                unsafeAtomicAdd(pm + 66, a2.z); unsafeAtomicAdd(pm + 67, a2.w);
                unsafeAtomicAdd(pm + 96, a3.x); unsafeAtomicAdd(pm + 97, a3.y);
                unsafeAtomicAdd(pm + 98, a3.z); unsafeAtomicAdd(pm + 99, a3.w);
                unsafeAtomicAdd(ps +  0, a0.x * a0.x); unsafeAtomicAdd(ps +  1, a0.y * a0.y);
                unsafeAtomicAdd(ps +  2, a0.z * a0.z); unsafeAtomicAdd(ps +  3, a0.w * a0.w);
                unsafeAtomicAdd(ps + 32, a1.x * a1.x); unsafeAtomicAdd(ps + 33, a1.y * a1.y);
                unsafeAtomicAdd(ps + 34, a1.z * a1.z); unsafeAtomicAdd(ps + 35, a1.w * a1.w);
                unsafeAtomicAdd(ps + 64, a2.x * a2.x); unsafeAtomicAdd(ps + 65, a2.y * a2.y);
                unsafeAtomicAdd(ps + 66, a2.z * a2.z); unsafeAtomicAdd(ps + 67, a2.w * a2.w);
                unsafeAtomicAdd(ps + 96, a3.x * a3.x); unsafeAtomicAdd(ps + 97, a3.y * a3.y);
                unsafeAtomicAdd(ps + 98, a3.z * a3.z); unsafeAtomicAdd(ps + 99, a3.w * a3.w);
                if (l8 == 0) unsafeAtomicAdd(pc, 1.0f);
            }
        }
    }
    __syncthreads();

    const int gbase = g * CG;
    const int cmax  = min(CG, classes - gbase);
    const int total = cmax * ROWLEN;
    float* gout = out + (size_t)gbase * ROWLEN;
    for (int i = tid; i < total; i += T2) {
        const float vv = part[i];
        if (vv != 0.0f) unsafeAtomicAdd(&gout[i], vv);
    }
}

// ---------------------------------------------------- fallback (round 1) ---
constexpr int FB_T = 512;
constexpr int FB_W = FB_T / 64;

__global__ __launch_bounds__(FB_T, 2)
void fb_kernel(const float* __restrict__ X, const int* __restrict__ labels,
               float* __restrict__ out, int N, int classes, int rpc)
{
    __shared__ float part[CG * ROWLEN];
    const int tid = threadIdx.x, lane = tid & 63, wid = tid >> 6;
    const int gbase = blockIdx.y * CG;
    for (int i = tid; i < CG * ROWLEN; i += FB_T) part[i] = 0.0f;
    __syncthreads();
    const long long row0 = (long long)blockIdx.x * rpc;
    int rows = rpc;
    if (row0 + rows > N) rows = (int)((long long)N - row0);
    for (int base = wid * 64; base < rows; base += FB_W * 64) {
        const int nb = min(64, rows - base);
        int lab = -1;
        if (lane < nb) lab = labels[row0 + base + lane];
        const int lc = lab - gbase;
        const bool in = (lab >= 0) && (lc >= 0) && (lc < CG) && (lab < classes);
        unsigned long long mask = __ballot(in);
        while (mask) {
            const int j = __ffsll((long long)mask) - 1;
            mask &= mask - 1;
            const int c = __shfl(lc, j);
            const size_t ridx = (size_t)(row0 + base + j) * DIM;
            const float x0 = X[ridx + lane];
            const float x1 = X[ridx + lane + 64];
            float* p = &part[c * ROWLEN];
            unsafeAtomicAdd(&p[1 + lane], x0);
            unsafeAtomicAdd(&p[65 + lane], x1);
            unsafeAtomicAdd(&p[129 + lane], x0 * x0);
            unsafeAtomicAdd(&p[193 + lane], x1 * x1);
            if (lane == 0) unsafeAtomicAdd(&p[0], 1.0f);
        }
    }
    __syncthreads();
    const int cmax = min(CG, classes - gbase);
    float* gout = out + (size_t)gbase * ROWLEN;
    for (int i = tid; i < cmax * ROWLEN; i += FB_T) {
        const float vv = part[i];
        if (vv != 0.0f) unsafeAtomicAdd(&gout[i], vv);
    }
}

// ------------------------------------------------------------------ launch --
extern "C" void kernel_launch(void* const* d_in, const int* in_sizes, int n_in,
                              void* d_out, int out_size, void* d_ws, size_t ws_size,
                              hipStream_t stream)
{
    const float* X      = (const float*)d_in[0];
    const int*   labels = (const int*)d_in[1];
    float*       out    = (float*)d_out;

    const int N       = in_sizes[1];
    const int classes = out_size / ROWLEN;
    const int groups  = (classes + CG - 1) / CG;

    hipMemsetAsync(d_out, 0, (size_t)out_size * sizeof(float), stream);

    const size_t need = 1024 + (size_t)N * 4;
    const bool fast = (ws_size >= need) && (N <= (1 << 25)) && (groups <= 64);

    if (fast) {
        unsigned* hist   = (unsigned*)d_ws;                    // 64 u32
        unsigned* off    = (unsigned*)((char*)d_ws + 256);     // 65 u32
        unsigned* cursor = (unsigned*)((char*)d_ws + 768);     // 64 u32
        unsigned* idx    = (unsigned*)((char*)d_ws + 1024);    // N u32

        hipMemsetAsync(d_ws, 0, 1024, stream);
        hist_kernel<<<1024, 256, 0, stream>>>(labels, N, classes, hist);
        prefix_kernel<<<1, 64, 0, stream>>>(hist, off, cursor, groups);
        const int sblocks = (N + SCAT_T * SCAT_IT - 1) / (SCAT_T * SCAT_IT);
        scatter_kernel<<<sblocks, SCAT_T, 0, stream>>>(labels, N, classes,
                                                       cursor, idx);
        const int slices = (N + SLICE - 1) / SLICE;
        dim3 grid(slices, groups);
        accum_kernel<<<grid, T2, 0, stream>>>(X, idx, off, out, classes);
    } else {
        const int target_chunks = 32;
        int rpc = (N + target_chunks - 1) / target_chunks;
        const int batch = FB_W * 64;
        rpc = ((rpc + batch - 1) / batch) * batch;
        const int chunks = (N + rpc - 1) / rpc;
        dim3 grid(chunks, groups);
        fb_kernel<<<grid, FB_T, 0, stream>>>(X, labels, out, N, classes, rpc);
    }
}

// Round 3
// 255.658 us; speedup vs baseline: 29.0898x; 29.0898x over previous
//
#include <hip/hip_runtime.h>

// DistributionTracker: per-label scatter-add of [count | sum(X) | sum(X^2)]
// X: (N, 128) fp32, labels: (N,) int32, out: (classes, 257) fp32 row-major.
//
// Round-3 design: full sort-by-class, then atomic-free register accumulation.
//   k1 hist   : per-block LDS histogram (1024 bins) -> global hist
//   k2 prefix : single-block Hillis-Steele scan -> off[0..classes], cursors
//   k3 scatter: per-block LDS hist + base, write row indices sorted by class
//   k4 accum  : one wave per class-quarter; lane owns cols {lane, lane+64};
//               8 unroll-slot register accumulators (16 coalesced 256B loads
//               in flight); NO LDS, NO atomics in the hot loop; flush with 4
//               global f32 atomics + count = segment length.
// Fallback: round-1 ballot-scan kernel (correct, slow) if ws too small.

constexpr int DIM    = 128;
constexpr int ROWLEN = 2 * DIM + 1;    // 257

// ---------------------------------------------------------------- binning --
__global__ void hist_kernel(const int* __restrict__ labels, int N, int classes,
                            unsigned* __restrict__ hist)
{
    __shared__ unsigned lh[1024];
    for (int i = threadIdx.x; i < 1024; i += blockDim.x) lh[i] = 0;
    __syncthreads();
    for (int i = blockIdx.x * blockDim.x + threadIdx.x; i < N;
         i += gridDim.x * blockDim.x) {
        const unsigned l = (unsigned)labels[i];
        if (l < (unsigned)classes) atomicAdd(&lh[l], 1u);
    }
    __syncthreads();
    for (int c = threadIdx.x; c < classes; c += blockDim.x)
        if (lh[c]) atomicAdd(&hist[c], lh[c]);
}

__global__ void prefix_kernel(const unsigned* __restrict__ hist,
                              unsigned* __restrict__ off,
                              unsigned* __restrict__ cursor, int classes)
{
    __shared__ unsigned s[1024];
    const int tid = threadIdx.x;
    s[tid] = (tid < classes) ? hist[tid] : 0u;
    __syncthreads();
    // inclusive Hillis-Steele scan over 1024
    for (int d = 1; d < 1024; d <<= 1) {
        unsigned v = (tid >= d) ? s[tid - d] : 0u;
        __syncthreads();
        s[tid] += v;
        __syncthreads();
    }
    if (tid == 0) { off[0] = 0; cursor[0] = 0; }
    if (tid < classes) {
        off[tid + 1] = s[tid];
        if (tid > 0) cursor[tid] = s[tid - 1];
    }
}

constexpr int SCAT_T  = 256;
constexpr int SCAT_IT = 16;            // 4096 rows per block

__global__ void scatter_kernel(const int* __restrict__ labels, int N, int classes,
                               unsigned* __restrict__ cursor,
                               unsigned* __restrict__ idx)
{
    __shared__ unsigned lh[1024], lbase[1024];
    const int tid  = threadIdx.x;
    const int tile = blockIdx.x * (SCAT_T * SCAT_IT);
    for (int i = tid; i < 1024; i += SCAT_T) lh[i] = 0;
    __syncthreads();

    int lab[SCAT_IT];
#pragma unroll
    for (int k = 0; k < SCAT_IT; ++k) {
        const int row = tile + k * SCAT_T + tid;
        lab[k] = -1;
        if (row < N) {
            const unsigned l = (unsigned)labels[row];
            if (l < (unsigned)classes) { lab[k] = (int)l; atomicAdd(&lh[l], 1u); }
        }
    }
    __syncthreads();
    for (int c = tid; c < classes; c += SCAT_T) {
        if (lh[c]) lbase[c] = atomicAdd(&cursor[c], lh[c]);
        lh[c] = 0;
    }
    __syncthreads();
#pragma unroll
    for (int k = 0; k < SCAT_IT; ++k) {
        if (lab[k] >= 0) {
            const unsigned l   = (unsigned)lab[k];
            const unsigned row = (unsigned)(tile + k * SCAT_T + tid);
            idx[lbase[l] + atomicAdd(&lh[l], 1u)] = row;
        }
    }
}

// ------------------------------------------------------------- accumulate --
constexpr int SPLIT = 4;               // waves per class
constexpr int U     = 8;               // rows in flight per wave

__global__ __launch_bounds__(64)
void accum_kernel(const float* __restrict__ X,
                  const unsigned* __restrict__ gidx,
                  const unsigned* __restrict__ off,
                  float* __restrict__ out)
{
    const int c = blockIdx.x / SPLIT;
    const int h = blockIdx.x % SPLIT;
    const unsigned s   = off[c];
    const unsigned cnt = off[c + 1] - s;
    if (cnt == 0) return;
    const unsigned s_h = s + (unsigned)(((unsigned long long)cnt * h) / SPLIT);
    const unsigned e_h = s + (unsigned)(((unsigned long long)cnt * (h + 1)) / SPLIT);
    if (s_h >= e_h) return;

    const int lane = threadIdx.x;

    float m0[U], m1[U], q0[U], q1[U];
#pragma unroll
    for (int u = 0; u < U; ++u) { m0[u] = m1[u] = q0[u] = q1[u] = 0.0f; }

    unsigned p = s_h;
    for (; p + U <= e_h; p += U) {
        const float* Xr[U];
#pragma unroll
        for (int u = 0; u < U; ++u) {
            const unsigned r = __builtin_amdgcn_readfirstlane(gidx[p + u]);
            Xr[u] = X + (size_t)r * DIM;
        }
#pragma unroll
        for (int u = 0; u < U; ++u) {
            const float x0 = Xr[u][lane];
            const float x1 = Xr[u][lane + 64];
            m0[u] += x0; q0[u] += x0 * x0;
            m1[u] += x1; q1[u] += x1 * x1;
        }
    }
    for (; p < e_h; ++p) {
        const unsigned r = __builtin_amdgcn_readfirstlane(gidx[p]);
        const float x0 = X[(size_t)r * DIM + lane];
        const float x1 = X[(size_t)r * DIM + lane + 64];
        m0[0] += x0; q0[0] += x0 * x0;
        m1[0] += x1; q1[0] += x1 * x1;
    }

#pragma unroll
    for (int u = 1; u < U; ++u) {
        m0[0] += m0[u]; m1[0] += m1[u];
        q0[0] += q0[u]; q1[0] += q1[u];
    }

    float* po = out + (size_t)c * ROWLEN;
    unsafeAtomicAdd(po + 1   + lane, m0[0]);
    unsafeAtomicAdd(po + 65  + lane, m1[0]);
    unsafeAtomicAdd(po + 129 + lane, q0[0]);
    unsafeAtomicAdd(po + 193 + lane, q1[0]);
    if (lane == 0) unsafeAtomicAdd(po, (float)(e_h - s_h));
}

// ---------------------------------------------------- fallback (round 1) ---
constexpr int FB_T = 512;
constexpr int FB_W = FB_T / 64;
constexpr int FB_CG = 63;

__global__ __launch_bounds__(FB_T, 2)
void fb_kernel(const float* __restrict__ X, const int* __restrict__ labels,
               float* __restrict__ out, int N, int classes, int rpc)
{
    __shared__ float part[FB_CG * ROWLEN];
    const int tid = threadIdx.x, lane = tid & 63, wid = tid >> 6;
    const int gbase = blockIdx.y * FB_CG;
    for (int i = tid; i < FB_CG * ROWLEN; i += FB_T) part[i] = 0.0f;
    __syncthreads();
    const long long row0 = (long long)blockIdx.x * rpc;
    int rows = rpc;
    if (row0 + rows > N) rows = (int)((long long)N - row0);
    for (int base = wid * 64; base < rows; base += FB_W * 64) {
        const int nb = min(64, rows - base);
        int lab = -1;
        if (lane < nb) lab = labels[row0 + base + lane];
        const int lc = lab - gbase;
        const bool in = (lab >= 0) && (lc >= 0) && (lc < FB_CG) && (lab < classes);
        unsigned long long mask = __ballot(in);
        while (mask) {
            const int j = __ffsll((long long)mask) - 1;
            mask &= mask - 1;
            const int cc = __shfl(lc, j);
            const size_t ridx = (size_t)(row0 + base + j) * DIM;
            const float x0 = X[ridx + lane];
            const float x1 = X[ridx + lane + 64];
            float* pp = &part[cc * ROWLEN];
            unsafeAtomicAdd(&pp[1 + lane], x0);
            unsafeAtomicAdd(&pp[65 + lane], x1);
            unsafeAtomicAdd(&pp[129 + lane], x0 * x0);
            unsafeAtomicAdd(&pp[193 + lane], x1 * x1);
            if (lane == 0) unsafeAtomicAdd(&pp[0], 1.0f);
        }
    }
    __syncthreads();
    const int cmax = min(FB_CG, classes - gbase);
    float* gout = out + (size_t)gbase * ROWLEN;
    for (int i = tid; i < cmax * ROWLEN; i += FB_T) {
        const float vv = part[i];
        if (vv != 0.0f) unsafeAtomicAdd(&gout[i], vv);
    }
}

// ------------------------------------------------------------------ launch --
extern "C" void kernel_launch(void* const* d_in, const int* in_sizes, int n_in,
                              void* d_out, int out_size, void* d_ws, size_t ws_size,
                              hipStream_t stream)
{
    const float* X      = (const float*)d_in[0];
    const int*   labels = (const int*)d_in[1];
    float*       out    = (float*)d_out;

    const int N       = in_sizes[1];
    const int classes = out_size / ROWLEN;

    hipMemsetAsync(d_out, 0, (size_t)out_size * sizeof(float), stream);

    // ws layout: hist[1024] @0 | off[1025] @4096 (pad to 8192) | cursor[1024]
    //            @8192 | idx[N] @12288
    const size_t need = 12288 + (size_t)N * 4;
    const bool fast = (ws_size >= need) && (classes <= 1024);

    if (fast) {
        unsigned* hist   = (unsigned*)d_ws;
        unsigned* off    = (unsigned*)((char*)d_ws + 4096);
        unsigned* cursor = (unsigned*)((char*)d_ws + 8192);
        unsigned* idx    = (unsigned*)((char*)d_ws + 12288);

        hipMemsetAsync(d_ws, 0, 12288, stream);
        hist_kernel<<<512, 256, 0, stream>>>(labels, N, classes, hist);
        prefix_kernel<<<1, 1024, 0, stream>>>(hist, off, cursor, classes);
        const int sblocks = (N + SCAT_T * SCAT_IT - 1) / (SCAT_T * SCAT_IT);
        scatter_kernel<<<sblocks, SCAT_T, 0, stream>>>(labels, N, classes,
                                                       cursor, idx);
        accum_kernel<<<classes * SPLIT, 64, 0, stream>>>(X, idx, off, out);
    } else {
        const int groups = (classes + FB_CG - 1) / FB_CG;
        const int target_chunks = 32;
        int rpc = (N + target_chunks - 1) / target_chunks;
        const int batch = FB_W * 64;
        rpc = ((rpc + batch - 1) / batch) * batch;
        const int chunks = (N + rpc - 1) / rpc;
        dim3 grid(chunks, groups);
        fb_kernel<<<grid, FB_T, 0, stream>>>(X, labels, out, N, classes, rpc);
    }
}